// Round 5
// baseline (1044.207 us; speedup 1.0000x reference)
//
#include <hip/hip_runtime.h>

#define NN 100000
#define NETY 3
#define EE 200000
#define DH 128
#define NBINS (NETY * NN)
#define SCAN_B 1024

// ---------- bf16 helpers ----------
__device__ __forceinline__ float bf2f(unsigned short u) {
    return __uint_as_float(((unsigned int)u) << 16);
}
__device__ __forceinline__ unsigned short f2bf(float f) {
    unsigned int u = __float_as_uint(f);
    unsigned int r = ((u >> 16) & 1u) + 0x7fffu;   // round-to-nearest-even
    return (unsigned short)((u + r) >> 16);
}

// ---------- CSR build: histogram by (etype, dst) ----------
__global__ void hist_kernel(const int* __restrict__ dst, int* __restrict__ cnt) {
    int tid = blockIdx.x * blockDim.x + threadIdx.x;
    if (tid >= NETY * EE) return;
    int e = tid / EE;
    atomicAdd(&cnt[e * NN + dst[tid]], 1);
}

// ---------- exclusive scan over NBINS ints (3 kernels) ----------
__global__ void scan1_kernel(const int* __restrict__ in, int* __restrict__ out,
                             int* __restrict__ bsum, int N) {
    __shared__ int s[256];
    int t = threadIdx.x;
    int base = blockIdx.x * SCAN_B + t * 4;
    int v0 = base + 0 < N ? in[base + 0] : 0;
    int v1 = base + 1 < N ? in[base + 1] : 0;
    int v2 = base + 2 < N ? in[base + 2] : 0;
    int v3 = base + 3 < N ? in[base + 3] : 0;
    int sum = v0 + v1 + v2 + v3;
    s[t] = sum;
    __syncthreads();
    for (int off = 1; off < 256; off <<= 1) {
        int x = (t >= off) ? s[t - off] : 0;
        __syncthreads();
        s[t] += x;
        __syncthreads();
    }
    int excl = s[t] - sum;
    if (base + 0 < N) out[base + 0] = excl;
    excl += v0;
    if (base + 1 < N) out[base + 1] = excl;
    excl += v1;
    if (base + 2 < N) out[base + 2] = excl;
    excl += v2;
    if (base + 3 < N) out[base + 3] = excl;
    if (t == 255) bsum[blockIdx.x] = s[255];
}

__global__ void scan2_kernel(int* __restrict__ bsum, int NB) {
    __shared__ int s[512];
    int t = threadIdx.x;
    int v = (t < NB) ? bsum[t] : 0;
    s[t] = v;
    __syncthreads();
    for (int off = 1; off < 512; off <<= 1) {
        int x = (t >= off) ? s[t - off] : 0;
        __syncthreads();
        s[t] += x;
        __syncthreads();
    }
    if (t < NB) bsum[t] = s[t] - v;   // exclusive
}

__global__ void scan3_kernel(int* __restrict__ out, const int* __restrict__ bsum, int N) {
    int add = bsum[blockIdx.x];
    int base = blockIdx.x * SCAN_B + threadIdx.x * 4;
    if (base + 0 < N) out[base + 0] += add;
    if (base + 1 < N) out[base + 1] += add;
    if (base + 2 < N) out[base + 2] += add;
    if (base + 3 < N) out[base + 3] += add;
}

// ---------- scatter edges into CSR (off becomes END pointers) ----------
__global__ void scatter_kernel(const int* __restrict__ src, const int* __restrict__ dst,
                               int* __restrict__ off, int* __restrict__ sorted) {
    int tid = blockIdx.x * blockDim.x + threadIdx.x;
    if (tid >= NETY * EE) return;
    int e = tid / EE;
    int pos = atomicAdd(&off[e * NN + dst[tid]], 1);
    sorted[pos] = src[tid];
}

// ---------- fused layer: CSR mean-gather (3 etypes) -> LDS, one K=3*DIN GEMM, write ----
// out[n] = concat_e(mean_e(feat)) @ vstack_e(W_e) + sum_e mask_e * b_e
// block = 256 threads = 4 waves, 32 nodes/block.
// Phase A: wave wv gathers nodes wv*8..wv*8+7; lane owns DIN/64 columns. Means -> bf16 LDS.
// Phase B: K3=3*DIN GEMM, 64-row fp32 W panels in LDS; thread (hg,ng): 4 nodes x 4 cols.
template <int DIN, bool BF16IN, bool BF16OUT>
__launch_bounds__(256)
__global__ void fused_layer_kernel(const void* __restrict__ feat_v,
                                   const int* __restrict__ sorted,
                                   const int* __restrict__ off,
                                   const int* __restrict__ cnt,
                                   const float* __restrict__ W,     // [3*DIN][128] (stacked)
                                   const float* __restrict__ bias,  // [3][128]
                                   void* __restrict__ out_v) {
    constexpr int K3 = 3 * DIN;
    __shared__ unsigned short s_agg[32 * K3];   // bf16 means: 12.3 KB (D64) / 24.6 KB (D128)
    __shared__ float s_W[64 * DH];              // 32 KB fp32 panel
    __shared__ float s_mask[NETY][32];

    const int t = threadIdx.x;
    const int n0 = blockIdx.x * 32;             // NN % 32 == 0
    const int wv = t >> 6;
    const int lane = t & 63;

    // ---- phase A: per-etype means into s_agg (bf16), masks into s_mask ----
    for (int ni = 0; ni < 8; ++ni) {
        const int nl = wv * 8 + ni;
        const int node = n0 + nl;
        #pragma unroll
        for (int e = 0; e < NETY; ++e) {
            const int c   = cnt[e * NN + node];
            const int end = off[e * NN + node];
            const int beg = end - c;
            if constexpr (BF16IN) {
                // DIN=128 bf16 input, leaky_relu fused on load; lane owns cols 2*lane, 2*lane+1
                const unsigned short* feat = (const unsigned short*)feat_v;
                float a0 = 0.f, a1 = 0.f;
                for (int i = beg; i < end; ++i) {
                    const int s = sorted[i];   // wave-uniform
                    ushort2 u = *reinterpret_cast<const ushort2*>(
                        feat + (size_t)s * DIN + lane * 2);
                    float f0 = bf2f(u.x), f1 = bf2f(u.y);
                    a0 += f0 > 0.f ? f0 : 0.01f * f0;
                    a1 += f1 > 0.f ? f1 : 0.01f * f1;
                }
                const float inv = c > 0 ? 1.f / (float)c : 0.f;
                ushort2 o;
                o.x = f2bf(a0 * inv);
                o.y = f2bf(a1 * inv);
                *reinterpret_cast<ushort2*>(&s_agg[nl * K3 + e * DIN + lane * 2]) = o;
            } else {
                // DIN=64 fp32 input; lane owns col lane
                const float* feat = (const float*)feat_v;
                float a = 0.f;
                for (int i = beg; i < end; ++i) {
                    const int s = sorted[i];
                    a += feat[(size_t)s * DIN + lane];
                }
                const float inv = c > 0 ? 1.f / (float)c : 0.f;
                s_agg[nl * K3 + e * DIN + lane] = f2bf(a * inv);
            }
            if (lane == 0) s_mask[e][nl] = c > 0 ? 1.f : 0.f;
        }
    }

    // ---- phase B: GEMM [32 x K3] @ [K3 x 128] ----
    const int hg = t & 31;
    const int ng = t >> 5;
    float acc[4][4] = {};

    for (int ph = 0; ph < K3 / 64; ++ph) {
        __syncthreads();   // phase-A complete (ph==0) / prev panel consumed
        {
            const float4* Wg = reinterpret_cast<const float4*>(W + (size_t)ph * 64 * DH);
            float4* sW4 = reinterpret_cast<float4*>(s_W);
            #pragma unroll
            for (int i = 0; i < 8; ++i) sW4[t + i * 256] = Wg[t + i * 256];
        }
        __syncthreads();
        const float4* Wv = reinterpret_cast<const float4*>(s_W);
        #pragma unroll
        for (int d4 = 0; d4 < 16; ++d4) {
            float a[4][4];
            #pragma unroll
            for (int i = 0; i < 4; ++i) {
                ushort4 u = *reinterpret_cast<const ushort4*>(
                    &s_agg[(ng + i * 8) * K3 + ph * 64 + d4 * 4]);
                a[i][0] = bf2f(u.x); a[i][1] = bf2f(u.y);
                a[i][2] = bf2f(u.z); a[i][3] = bf2f(u.w);
            }
            #pragma unroll
            for (int j = 0; j < 4; ++j) {
                float4 w = Wv[(d4 * 4 + j) * 32 + hg];
                #pragma unroll
                for (int i = 0; i < 4; ++i) {
                    acc[i][0] += a[i][j] * w.x;
                    acc[i][1] += a[i][j] * w.y;
                    acc[i][2] += a[i][j] * w.z;
                    acc[i][3] += a[i][j] * w.w;
                }
            }
        }
    }

    // ---- epilogue: masked bias, single write ----
    float4 b0 = *reinterpret_cast<const float4*>(bias + 0 * DH + hg * 4);
    float4 b1 = *reinterpret_cast<const float4*>(bias + 1 * DH + hg * 4);
    float4 b2 = *reinterpret_cast<const float4*>(bias + 2 * DH + hg * 4);
    #pragma unroll
    for (int i = 0; i < 4; ++i) {
        const int nl = ng + i * 8;
        const float m0 = s_mask[0][nl], m1 = s_mask[1][nl], m2 = s_mask[2][nl];
        float v0 = acc[i][0] + m0 * b0.x + m1 * b1.x + m2 * b2.x;
        float v1 = acc[i][1] + m0 * b0.y + m1 * b1.y + m2 * b2.y;
        float v2 = acc[i][2] + m0 * b0.z + m1 * b1.z + m2 * b2.z;
        float v3 = acc[i][3] + m0 * b0.w + m1 * b1.w + m2 * b2.w;
        if constexpr (BF16OUT) {
            unsigned short* op = (unsigned short*)out_v + (size_t)(n0 + nl) * DH + hg * 4;
            ushort4 o;
            o.x = f2bf(v0); o.y = f2bf(v1); o.z = f2bf(v2); o.w = f2bf(v3);
            *reinterpret_cast<ushort4*>(op) = o;
        } else {
            float* op = (float*)out_v + (size_t)(n0 + nl) * DH + hg * 4;
            *reinterpret_cast<float4*>(op) = make_float4(v0, v1, v2, v3);
        }
    }
}

extern "C" void kernel_launch(void* const* d_in, const int* in_sizes, int n_in,
                              void* d_out, int out_size, void* d_ws, size_t ws_size,
                              hipStream_t stream) {
    const float* x   = (const float*)d_in[0];   // [NN, 64]
    const int* esrc  = (const int*)d_in[1];     // [3, EE]
    const int* edst  = (const int*)d_in[2];     // [3, EE]
    const float* W1  = (const float*)d_in[3];   // [3, 64, 128]  == [192][128] stacked
    const float* b1  = (const float*)d_in[4];   // [3, 128]
    const float* W2  = (const float*)d_in[5];   // [3, 128, 128] == [384][128] stacked
    const float* b2  = (const float*)d_in[6];   // [3, 128]
    float* out = (float*)d_out;                 // [NN, 128] fp32

    // workspace: CSR (4.8 MB) + h bf16 (25.6 MB)
    int* cnt    = (int*)d_ws;                   // [3*NN]
    int* off    = cnt + NBINS;                  // [3*NN] -> end-pointers after scatter
    int* sorted = off + NBINS;                  // [3*EE]
    int* bsum   = sorted + NETY * EE;           // [<=512]
    unsigned short* h = (unsigned short*)(bsum + 512);   // [NN*128] bf16

    const int NB = (NBINS + SCAN_B - 1) / SCAN_B;   // 293

    // ---- CSR build (shared by both layers) ----
    hipMemsetAsync(cnt, 0, sizeof(int) * NBINS, stream);
    hist_kernel<<<(NETY * EE + 255) / 256, 256, 0, stream>>>(edst, cnt);
    scan1_kernel<<<NB, 256, 0, stream>>>(cnt, off, bsum, NBINS);
    scan2_kernel<<<1, 512, 0, stream>>>(bsum, NB);
    scan3_kernel<<<NB, 256, 0, stream>>>(off, bsum, NBINS);
    scatter_kernel<<<(NETY * EE + 255) / 256, 256, 0, stream>>>(esrc, edst, off, sorted);

    // ---- layer 1: h = fused(x) (bf16 out) ----
    fused_layer_kernel<64, false, true><<<NN / 32, 256, 0, stream>>>(
        x, sorted, off, cnt, W1, b1, h);

    // ---- layer 2: out = fused(leaky_relu(h)) (fp32 out) ----
    fused_layer_kernel<128, true, false><<<NN / 32, 256, 0, stream>>>(
        h, sorted, off, cnt, W2, b2, out);
}

// Round 6
// 290.240 us; speedup vs baseline: 3.5977x; 3.5977x over previous
//
#include <hip/hip_runtime.h>

#define NN 100000
#define NETY 3
#define EE 200000
#define DH 128
#define NBINS (NETY * NN)
#define SCAN_B 1024

typedef __attribute__((ext_vector_type(8))) short short8;
typedef __attribute__((ext_vector_type(4))) short short4v;
typedef __attribute__((ext_vector_type(4))) float f32x4;

// ---------- bf16 helpers ----------
__device__ __forceinline__ float bf2f(unsigned short u) {
    return __uint_as_float(((unsigned int)u) << 16);
}
__device__ __forceinline__ unsigned short f2bf(float f) {
    unsigned int u = __float_as_uint(f);
    unsigned int r = ((u >> 16) & 1u) + 0x7fffu;   // round-to-nearest-even
    return (unsigned short)((u + r) >> 16);
}

// ---------- CSR build: histogram by (etype, dst) ----------
__global__ void hist_kernel(const int* __restrict__ dst, int* __restrict__ cnt) {
    int tid = blockIdx.x * blockDim.x + threadIdx.x;
    if (tid >= NETY * EE) return;
    int e = tid / EE;
    atomicAdd(&cnt[e * NN + dst[tid]], 1);
}

// ---------- exclusive scan over NBINS ints (3 kernels) ----------
__global__ void scan1_kernel(const int* __restrict__ in, int* __restrict__ out,
                             int* __restrict__ bsum, int N) {
    __shared__ int s[256];
    int t = threadIdx.x;
    int base = blockIdx.x * SCAN_B + t * 4;
    int v0 = base + 0 < N ? in[base + 0] : 0;
    int v1 = base + 1 < N ? in[base + 1] : 0;
    int v2 = base + 2 < N ? in[base + 2] : 0;
    int v3 = base + 3 < N ? in[base + 3] : 0;
    int sum = v0 + v1 + v2 + v3;
    s[t] = sum;
    __syncthreads();
    for (int off = 1; off < 256; off <<= 1) {
        int x = (t >= off) ? s[t - off] : 0;
        __syncthreads();
        s[t] += x;
        __syncthreads();
    }
    int excl = s[t] - sum;
    if (base + 0 < N) out[base + 0] = excl;
    excl += v0;
    if (base + 1 < N) out[base + 1] = excl;
    excl += v1;
    if (base + 2 < N) out[base + 2] = excl;
    excl += v2;
    if (base + 3 < N) out[base + 3] = excl;
    if (t == 255) bsum[blockIdx.x] = s[255];
}

__global__ void scan2_kernel(int* __restrict__ bsum, int NB) {
    __shared__ int s[512];
    int t = threadIdx.x;
    int v = (t < NB) ? bsum[t] : 0;
    s[t] = v;
    __syncthreads();
    for (int off = 1; off < 512; off <<= 1) {
        int x = (t >= off) ? s[t - off] : 0;
        __syncthreads();
        s[t] += x;
        __syncthreads();
    }
    if (t < NB) bsum[t] = s[t] - v;   // exclusive
}

__global__ void scan3_kernel(int* __restrict__ out, const int* __restrict__ bsum, int N) {
    int add = bsum[blockIdx.x];
    int base = blockIdx.x * SCAN_B + threadIdx.x * 4;
    if (base + 0 < N) out[base + 0] += add;
    if (base + 1 < N) out[base + 1] += add;
    if (base + 2 < N) out[base + 2] += add;
    if (base + 3 < N) out[base + 3] += add;
}

// ---------- scatter edges into CSR (off becomes END pointers) ----------
__global__ void scatter_kernel(const int* __restrict__ src, const int* __restrict__ dst,
                               int* __restrict__ off, int* __restrict__ sorted) {
    int tid = blockIdx.x * blockDim.x + threadIdx.x;
    if (tid >= NETY * EE) return;
    int e = tid / EE;
    int pos = atomicAdd(&off[e * NN + dst[tid]], 1);
    sorted[pos] = src[tid];
}

// ---------- W -> bf16 fragment-swizzled layout for mfma_f32_16x16x32_bf16 ----------
// Wfrag[((ks*8 + nf)*64 + l)*8 + j] = bf16( W[ks*32 + (l>>4)*8 + j][nf*16 + (l&15)] )
template <int K3>
__global__ void wprep_kernel(const float* __restrict__ W, unsigned short* __restrict__ Wf) {
    constexpr int NK = K3 / 32;
    int tid = blockIdx.x * 256 + threadIdx.x;
    if (tid >= NK * 8 * 64) return;
    int l = tid & 63;
    int nfks = tid >> 6;
    int nf = nfks & 7, ks = nfks >> 3;
    int k0 = ks * 32 + (l >> 4) * 8;
    int col = nf * 16 + (l & 15);
    short8 o;
    #pragma unroll
    for (int j = 0; j < 8; ++j)
        o[j] = (short)f2bf(W[(size_t)(k0 + j) * DH + col]);
    *reinterpret_cast<short8*>(Wf + (size_t)tid * 8) = o;
}

// ---------- CSR mean aggregate: 16-lane group per (etype,node) bin ----------
// DIN=64 fp32 input (layer 1) / DIN=128 bf16 input + leaky_relu (layer 2).
// Writes bf16 means into stacked agg[node][e*DIN + col], zero if no in-edges.
template <int DIN, bool BF16IN, int K3>
__global__ void csr_mean_kernel(const void* __restrict__ feat_v,
                                const int* __restrict__ sorted,
                                const int* __restrict__ off,
                                const int* __restrict__ cnt,
                                unsigned short* __restrict__ agg) {
    const int t = threadIdx.x;
    const int g = (blockIdx.x * 256 + t) >> 4;      // bin id = e*NN + node
    if (g >= NBINS) return;
    const int sub = t & 15;
    const int e = g / NN;
    const int node = g - e * NN;
    const int c = cnt[g];
    const int end = off[g];
    const int beg = end - c;
    const float inv = c > 0 ? 1.f / (float)c : 0.f;

    if constexpr (BF16IN) {
        const unsigned short* feat = (const unsigned short*)feat_v;
        float a[8] = {0.f, 0.f, 0.f, 0.f, 0.f, 0.f, 0.f, 0.f};
        for (int i = beg; i < end; ++i) {
            const int s = sorted[i];
            short8 u = *reinterpret_cast<const short8*>(feat + (size_t)s * DIN + sub * 8);
            #pragma unroll
            for (int j = 0; j < 8; ++j) {
                float f = bf2f((unsigned short)u[j]);
                a[j] += f > 0.f ? f : 0.01f * f;
            }
        }
        short8 o;
        #pragma unroll
        for (int j = 0; j < 8; ++j) o[j] = (short)f2bf(a[j] * inv);
        *reinterpret_cast<short8*>(agg + (size_t)node * K3 + e * DIN + sub * 8) = o;
    } else {
        const float* feat = (const float*)feat_v;
        float4 a = make_float4(0.f, 0.f, 0.f, 0.f);
        for (int i = beg; i < end; ++i) {
            const int s = sorted[i];
            float4 v = *reinterpret_cast<const float4*>(feat + (size_t)s * DIN + sub * 4);
            a.x += v.x; a.y += v.y; a.z += v.z; a.w += v.w;
        }
        short4v o;
        o[0] = (short)f2bf(a.x * inv);
        o[1] = (short)f2bf(a.y * inv);
        o[2] = (short)f2bf(a.z * inv);
        o[3] = (short)f2bf(a.w * inv);
        *reinterpret_cast<short4v*>(agg + (size_t)node * K3 + e * DIN + sub * 4) = o;
    }
}

// ---------- MFMA transform: out[32 x 128] = A[32 x K3] @ Wfrag + masked bias ----------
// 256 thr = 4 waves; wave wv: rows (wv&1)*16..+16, cols (wv>>1)*64..+64 (4 nfrags).
// A staged in LDS, stride K3+8 bf16 (uniform bank windows for ds_read_b128).
template <int K3, bool BF16OUT>
__launch_bounds__(256)
__global__ void mfma_transform_kernel(const unsigned short* __restrict__ agg,  // [NN][K3] bf16
                                      const int* __restrict__ cnt,             // [3][NN]
                                      const unsigned short* __restrict__ Wf,   // fragment-swizzled
                                      const float* __restrict__ bias,          // [3][128]
                                      void* __restrict__ out_v) {
    constexpr int NK = K3 / 32;
    constexpr int SP = K3 + 8;     // padded LDS stride (bf16 units)
    constexpr int CPR = K3 / 8;    // 16B chunks per row
    __shared__ unsigned short s_a[32 * SP];
    __shared__ float s_mask[NETY][32];

    const int t = threadIdx.x;
    const int n0 = blockIdx.x * 32;           // NN % 32 == 0

    if (t < 96) {
        int e = t >> 5, nl = t & 31;
        s_mask[e][nl] = cnt[e * NN + n0 + nl] > 0 ? 1.f : 0.f;
    }
    for (int c = t; c < 32 * CPR; c += 256) {
        int r = c / CPR, cc = c - r * CPR;
        short8 v = *reinterpret_cast<const short8*>(agg + (size_t)(n0 + r) * K3 + cc * 8);
        *reinterpret_cast<short8*>(&s_a[r * SP + cc * 8]) = v;
    }
    __syncthreads();

    const int wv = t >> 6, l = t & 63;
    const int rowbase = (wv & 1) * 16;
    const int nfbase = (wv >> 1) * 4;
    const int lr = l & 15, lk = l >> 4;

    f32x4 acc[4] = {{0.f,0.f,0.f,0.f},{0.f,0.f,0.f,0.f},{0.f,0.f,0.f,0.f},{0.f,0.f,0.f,0.f}};
    const unsigned short* sa = &s_a[(rowbase + lr) * SP + lk * 8];

    #pragma unroll
    for (int ks = 0; ks < NK; ++ks) {
        short8 af = *reinterpret_cast<const short8*>(sa + ks * 32);
        const unsigned short* wb = Wf + ((size_t)(ks * 8 + nfbase) * 64 + l) * 8;
        #pragma unroll
        for (int nf = 0; nf < 4; ++nf) {
            short8 bf = *reinterpret_cast<const short8*>(wb + (size_t)nf * 64 * 8);
            acc[nf] = __builtin_amdgcn_mfma_f32_16x16x32_bf16(af, bf, acc[nf], 0, 0, 0);
        }
    }

    // epilogue: D frag -> (row = rowbase + lk*4 + v, col = nfbase*16 + nf*16 + lr)
    #pragma unroll
    for (int nf = 0; nf < 4; ++nf) {
        const int col = (nfbase + nf) * 16 + lr;
        const float b0 = bias[0 * DH + col];
        const float b1 = bias[1 * DH + col];
        const float b2 = bias[2 * DH + col];
        #pragma unroll
        for (int v = 0; v < 4; ++v) {
            const int row = rowbase + lk * 4 + v;
            const float val = acc[nf][v] + s_mask[0][row] * b0
                                         + s_mask[1][row] * b1
                                         + s_mask[2][row] * b2;
            if constexpr (BF16OUT)
                ((unsigned short*)out_v)[(size_t)(n0 + row) * DH + col] = f2bf(val);
            else
                ((float*)out_v)[(size_t)(n0 + row) * DH + col] = val;
        }
    }
}

extern "C" void kernel_launch(void* const* d_in, const int* in_sizes, int n_in,
                              void* d_out, int out_size, void* d_ws, size_t ws_size,
                              hipStream_t stream) {
    const float* x   = (const float*)d_in[0];   // [NN, 64]
    const int* esrc  = (const int*)d_in[1];     // [3, EE]
    const int* edst  = (const int*)d_in[2];     // [3, EE]
    const float* W1  = (const float*)d_in[3];   // [3, 64, 128]  == [192][128] stacked
    const float* b1  = (const float*)d_in[4];   // [3, 128]
    const float* W2  = (const float*)d_in[5];   // [3, 128, 128] == [384][128] stacked
    const float* b2  = (const float*)d_in[6];   // [3, 128]
    float* out = (float*)d_out;                 // [NN, 128] fp32

    // workspace layout (~107 MB)
    int* cnt    = (int*)d_ws;                        // [3*NN]
    int* off    = cnt + NBINS;                       // [3*NN] -> end-pointers after scatter
    int* sorted = off + NBINS;                       // [3*EE]
    int* bsum   = sorted + NETY * EE;                // [<=512]
    unsigned short* Wf1 = (unsigned short*)(bsum + 512);        // [192*128]
    unsigned short* Wf2 = Wf1 + 192 * DH;                       // [384*128]
    unsigned short* agg = Wf2 + 384 * DH;                       // [NN*384] bf16 (shared L1/L2)
    unsigned short* h   = agg + (size_t)NN * 384;               // [NN*128] bf16

    const int NB = (NBINS + SCAN_B - 1) / SCAN_B;   // 293

    // ---- W fragment prep (no deps) ----
    wprep_kernel<192><<<(192 / 32 * 8 * 64 + 255) / 256, 256, 0, stream>>>(W1, Wf1);
    wprep_kernel<384><<<(384 / 32 * 8 * 64 + 255) / 256, 256, 0, stream>>>(W2, Wf2);

    // ---- CSR build (shared by both layers) ----
    hipMemsetAsync(cnt, 0, sizeof(int) * NBINS, stream);
    hist_kernel<<<(NETY * EE + 255) / 256, 256, 0, stream>>>(edst, cnt);
    scan1_kernel<<<NB, 256, 0, stream>>>(cnt, off, bsum, NBINS);
    scan2_kernel<<<1, 512, 0, stream>>>(bsum, NB);
    scan3_kernel<<<NB, 256, 0, stream>>>(off, bsum, NBINS);
    scatter_kernel<<<(NETY * EE + 255) / 256, 256, 0, stream>>>(esrc, edst, off, sorted);

    // ---- layer 1: agg = per-etype means of x (bf16, [NN][192]) ; h = A@W1 + bias (bf16) ----
    csr_mean_kernel<64, false, 192><<<NBINS / 16, 256, 0, stream>>>(
        x, sorted, off, cnt, agg);
    mfma_transform_kernel<192, true><<<NN / 32, 256, 0, stream>>>(
        agg, cnt, Wf1, b1, h);

    // ---- layer 2: agg = means of leaky_relu(h) (bf16, [NN][384]) ; out = A@W2 + bias ----
    csr_mean_kernel<128, true, 384><<<NBINS / 16, 256, 0, stream>>>(
        h, sorted, off, cnt, agg);
    mfma_transform_kernel<384, false><<<NN / 32, 256, 0, stream>>>(
        agg, cnt, Wf2, b2, out);
}

// Round 7
// 248.712 us; speedup vs baseline: 4.1984x; 1.1670x over previous
//
#include <hip/hip_runtime.h>

#define NN 100000
#define NETY 3
#define EE 200000
#define DH 128
#define NBINS (NETY * NN)
#define CAP 32
#define SCAT_B ((NETY * EE + 255) / 256)   // 2344

typedef __attribute__((ext_vector_type(8))) short short8;
typedef __attribute__((ext_vector_type(4))) short short4v;
typedef __attribute__((ext_vector_type(4))) float f32x4;

// ---------- bf16 helpers ----------
__device__ __forceinline__ float bf2f(unsigned short u) {
    return __uint_as_float(((unsigned int)u) << 16);
}
__device__ __forceinline__ unsigned short f2bf(float f) {
    unsigned int u = __float_as_uint(f);
    unsigned int r = ((u >> 16) & 1u) + 0x7fffu;   // round-to-nearest-even
    return (unsigned short)((u + r) >> 16);
}

// ---------- W -> bf16 fragment-swizzled layout for mfma_f32_16x16x32_bf16 ----------
// Wf[((ks*8 + nf)*64 + l)*8 + j] = bf16( W[ks*32 + (l>>4)*8 + j][nf*16 + (l&15)] )
template <int K3>
__device__ __forceinline__ void wprep_body(const float* __restrict__ W,
                                           unsigned short* __restrict__ Wf, int tid) {
    int l = tid & 63;
    int nfks = tid >> 6;
    int nf = nfks & 7, ks = nfks >> 3;
    int k0 = ks * 32 + (l >> 4) * 8;
    int col = nf * 16 + (l & 15);
    short8 o;
    #pragma unroll
    for (int j = 0; j < 8; ++j)
        o[j] = (short)f2bf(W[(size_t)(k0 + j) * DH + col]);
    *reinterpret_cast<short8*>(Wf + (size_t)tid * 8) = o;
}

// ---------- one kernel: edge->slot scatter (no scan needed) + both W preps ----------
// blocks [0, SCAT_B): scatter; [SCAT_B, +12): wprep<192>; [+12, +24 more): wprep<384>
__global__ void scatter_wprep_kernel(const int* __restrict__ esrc,
                                     const int* __restrict__ edst,
                                     int* __restrict__ cnt, int* __restrict__ slots,
                                     const float* __restrict__ W1,
                                     const float* __restrict__ W2,
                                     unsigned short* __restrict__ Wf1,
                                     unsigned short* __restrict__ Wf2) {
    const int bid = blockIdx.x;
    if (bid < SCAT_B) {
        int tid = bid * 256 + threadIdx.x;
        if (tid < NETY * EE) {
            int e = tid / EE;
            int bin = e * NN + edst[tid];
            int pos = atomicAdd(&cnt[bin], 1);
            if (pos < CAP) slots[(size_t)bin * CAP + pos] = esrc[tid];
        }
    } else if (bid < SCAT_B + 12) {
        wprep_body<192>(W1, Wf1, (bid - SCAT_B) * 256 + threadIdx.x);
    } else {
        wprep_body<384>(W2, Wf2, (bid - SCAT_B - 12) * 256 + threadIdx.x);
    }
}

// ---------- fused layer: slot-gather means -> LDS (bf16) -> MFMA GEMM -> write ----------
// 256 thr, 32 nodes/block. Gather: 16 groups x 16 lanes; group g walks 6 bins
// (nl in {g, 16+g} x 3 etypes); lane owns DIN/16 contiguous cols. Means to s_a (padded).
// GEMM: 4 waves; wave wv: rows (wv&1)*16, cols (wv>>1)*64; mfma_f32_16x16x32_bf16.
template <int DIN, bool BF16IN, bool BF16OUT>
__launch_bounds__(256)
__global__ void fused_layer_kernel(const void* __restrict__ feat_v,
                                   const int* __restrict__ slots,
                                   const int* __restrict__ cnt,
                                   const unsigned short* __restrict__ Wf,
                                   const float* __restrict__ bias,   // [3][128]
                                   void* __restrict__ out_v) {
    constexpr int K3 = 3 * DIN;
    constexpr int NK = K3 / 32;
    constexpr int SP = K3 + 8;          // padded LDS stride (bf16 units)
    __shared__ unsigned short s_a[32 * SP];   // 12.5 KB (L1) / 24.5 KB (L2)
    __shared__ float s_mask[NETY][32];

    const int t = threadIdx.x;
    const int n0 = blockIdx.x * 32;     // NN % 32 == 0
    const int g = t >> 4, sub = t & 15;

    // ---- phase A: slot-gather per-etype means into s_a ----
    #pragma unroll
    for (int bi = 0; bi < 6; ++bi) {
        const int b = bi * 16 + g;      // 0..95
        const int nl = b & 31;
        const int e = b >> 5;
        const int bin = e * NN + n0 + nl;
        const int c = cnt[bin];
        const int sb = bin * CAP;
        const float inv = c > 0 ? 1.f / (float)c : 0.f;
        if constexpr (BF16IN) {
            const unsigned short* feat = (const unsigned short*)feat_v;
            float a[8] = {0.f, 0.f, 0.f, 0.f, 0.f, 0.f, 0.f, 0.f};
            for (int i = 0; i < c; ++i) {
                const int s = slots[sb + i];
                short8 u = *reinterpret_cast<const short8*>(feat + (size_t)s * DIN + sub * 8);
                #pragma unroll
                for (int j = 0; j < 8; ++j) {
                    float f = bf2f((unsigned short)u[j]);
                    a[j] += f > 0.f ? f : 0.01f * f;     // fused leaky_relu
                }
            }
            short8 o;
            #pragma unroll
            for (int j = 0; j < 8; ++j) o[j] = (short)f2bf(a[j] * inv);
            *reinterpret_cast<short8*>(&s_a[nl * SP + e * DIN + sub * 8]) = o;
        } else {
            const float* feat = (const float*)feat_v;
            float4 a = make_float4(0.f, 0.f, 0.f, 0.f);
            for (int i = 0; i < c; ++i) {
                const int s = slots[sb + i];
                float4 v = *reinterpret_cast<const float4*>(feat + (size_t)s * DIN + sub * 4);
                a.x += v.x; a.y += v.y; a.z += v.z; a.w += v.w;
            }
            short4v o;
            o[0] = (short)f2bf(a.x * inv);
            o[1] = (short)f2bf(a.y * inv);
            o[2] = (short)f2bf(a.z * inv);
            o[3] = (short)f2bf(a.w * inv);
            *reinterpret_cast<short4v*>(&s_a[nl * SP + e * DIN + sub * 4]) = o;
        }
        if (sub == 0) s_mask[e][nl] = c > 0 ? 1.f : 0.f;
    }
    __syncthreads();

    // ---- phase B: [32 x K3] @ Wf -> [32 x 128] via MFMA ----
    const int wv = t >> 6, l = t & 63;
    const int rowbase = (wv & 1) * 16;
    const int nfbase = (wv >> 1) * 4;
    const int lr = l & 15, lk = l >> 4;

    f32x4 acc[4] = {{0.f,0.f,0.f,0.f},{0.f,0.f,0.f,0.f},{0.f,0.f,0.f,0.f},{0.f,0.f,0.f,0.f}};
    const unsigned short* sa = &s_a[(rowbase + lr) * SP + lk * 8];

    #pragma unroll
    for (int ks = 0; ks < NK; ++ks) {
        short8 af = *reinterpret_cast<const short8*>(sa + ks * 32);
        const unsigned short* wb = Wf + ((size_t)(ks * 8 + nfbase) * 64 + l) * 8;
        #pragma unroll
        for (int nf = 0; nf < 4; ++nf) {
            short8 bf = *reinterpret_cast<const short8*>(wb + (size_t)nf * 64 * 8);
            acc[nf] = __builtin_amdgcn_mfma_f32_16x16x32_bf16(af, bf, acc[nf], 0, 0, 0);
        }
    }

    // epilogue: D(row = rowbase + lk*4 + v, col = (nfbase+nf)*16 + lr) + masked bias
    #pragma unroll
    for (int nf = 0; nf < 4; ++nf) {
        const int col = (nfbase + nf) * 16 + lr;
        const float b0 = bias[0 * DH + col];
        const float b1 = bias[1 * DH + col];
        const float b2 = bias[2 * DH + col];
        #pragma unroll
        for (int v = 0; v < 4; ++v) {
            const int row = rowbase + lk * 4 + v;
            const float val = acc[nf][v] + s_mask[0][row] * b0
                                         + s_mask[1][row] * b1
                                         + s_mask[2][row] * b2;
            if constexpr (BF16OUT)
                ((unsigned short*)out_v)[(size_t)(n0 + row) * DH + col] = f2bf(val);
            else
                ((float*)out_v)[(size_t)(n0 + row) * DH + col] = val;
        }
    }
}

extern "C" void kernel_launch(void* const* d_in, const int* in_sizes, int n_in,
                              void* d_out, int out_size, void* d_ws, size_t ws_size,
                              hipStream_t stream) {
    const float* x   = (const float*)d_in[0];   // [NN, 64]
    const int* esrc  = (const int*)d_in[1];     // [3, EE]
    const int* edst  = (const int*)d_in[2];     // [3, EE]
    const float* W1  = (const float*)d_in[3];   // [3, 64, 128]
    const float* b1  = (const float*)d_in[4];   // [3, 128]
    const float* W2  = (const float*)d_in[5];   // [3, 128, 128]
    const float* b2  = (const float*)d_in[6];   // [3, 128]
    float* out = (float*)d_out;                 // [NN, 128] fp32

    // workspace layout (~65.4 MB)
    int* cnt    = (int*)d_ws;                               // [3*NN]
    int* slots  = cnt + NBINS;                              // [3*NN * CAP] = 38.4 MB
    unsigned short* Wf1 = (unsigned short*)(slots + (size_t)NBINS * CAP);  // [192*128]
    unsigned short* Wf2 = Wf1 + 192 * DH;                   // [384*128]
    unsigned short* h   = Wf2 + 384 * DH;                   // [NN*128] bf16

    // 1) zero bin counters
    hipMemsetAsync(cnt, 0, sizeof(int) * NBINS, stream);

    // 2) edge->slot scatter + W fragment prep (single kernel)
    scatter_wprep_kernel<<<SCAT_B + 12 + 24, 256, 0, stream>>>(
        esrc, edst, cnt, slots, W1, W2, Wf1, Wf2);

    // 3) layer 1: h = (concat_e mean_e(x)) @ W1 + masked bias   (bf16 out)
    fused_layer_kernel<64, false, true><<<NN / 32, 256, 0, stream>>>(
        x, slots, cnt, Wf1, b1, h);

    // 4) layer 2: out = (concat_e mean_e(lrelu(h))) @ W2 + masked bias   (fp32 out)
    fused_layer_kernel<128, true, false><<<NN / 32, 256, 0, stream>>>(
        h, slots, cnt, Wf2, b2, out);
}

// Round 8
// 207.461 us; speedup vs baseline: 5.0333x; 1.1988x over previous
//
#include <hip/hip_runtime.h>

#define NN 100000
#define NETY 3
#define EE 200000
#define DH 128
#define NBINS (NETY * NN)
#define CAP 32
#define SCAT_B ((NETY * EE + 255) / 256)   // 2344

typedef __attribute__((ext_vector_type(8))) short short8;
typedef __attribute__((ext_vector_type(4))) short short4v;
typedef __attribute__((ext_vector_type(4))) float f32x4;

// ---------- bf16 helpers ----------
__device__ __forceinline__ float bf2f(unsigned short u) {
    return __uint_as_float(((unsigned int)u) << 16);
}
__device__ __forceinline__ unsigned short f2bf(float f) {
    unsigned int u = __float_as_uint(f);
    unsigned int r = ((u >> 16) & 1u) + 0x7fffu;   // round-to-nearest-even
    return (unsigned short)((u + r) >> 16);
}
__device__ __forceinline__ float lrelu(float f) {
    return f > 0.f ? f : 0.01f * f;
}

// ---------- W -> bf16 fragment-swizzled layout for mfma_f32_16x16x32_bf16 ----------
// Wf[((ks*8 + nf)*64 + l)*8 + j] = bf16( W[ks*32 + (l>>4)*8 + j][nf*16 + (l&15)] )
template <int K3>
__device__ __forceinline__ void wprep_body(const float* __restrict__ W,
                                           unsigned short* __restrict__ Wf, int tid) {
    int l = tid & 63;
    int nfks = tid >> 6;
    int nf = nfks & 7, ks = nfks >> 3;
    int k0 = ks * 32 + (l >> 4) * 8;
    int col = nf * 16 + (l & 15);
    short8 o;
    #pragma unroll
    for (int j = 0; j < 8; ++j)
        o[j] = (short)f2bf(W[(size_t)(k0 + j) * DH + col]);
    *reinterpret_cast<short8*>(Wf + (size_t)tid * 8) = o;
}

// ---------- one kernel: edge->slot scatter (no scan needed) + both W preps ----------
__global__ void scatter_wprep_kernel(const int* __restrict__ esrc,
                                     const int* __restrict__ edst,
                                     int* __restrict__ cnt, int* __restrict__ slots,
                                     const float* __restrict__ W1,
                                     const float* __restrict__ W2,
                                     unsigned short* __restrict__ Wf1,
                                     unsigned short* __restrict__ Wf2) {
    const int bid = blockIdx.x;
    if (bid < SCAT_B) {
        int tid = bid * 256 + threadIdx.x;
        if (tid < NETY * EE) {
            int e = tid / EE;
            int bin = e * NN + edst[tid];
            int pos = atomicAdd(&cnt[bin], 1);
            if (pos < CAP) slots[(size_t)bin * CAP + pos] = esrc[tid];
        }
    } else if (bid < SCAT_B + 12) {
        wprep_body<192>(W1, Wf1, (bid - SCAT_B) * 256 + threadIdx.x);
    } else {
        wprep_body<384>(W2, Wf2, (bid - SCAT_B - 12) * 256 + threadIdx.x);
    }
}

// slot index j of a bin: register shfl for j<16, direct (rare, uniform) load for j>=16
__device__ __forceinline__ int get_slot(int slo, const int* __restrict__ slots,
                                        int sbase, int j) {
    int v = __shfl(slo, j & 15, 16);
    if (j >= 16) v = slots[sbase + j];
    return v;
}

// ---------- fused layer: slot-gather means -> LDS (bf16) -> MFMA GEMM -> write ----------
// 256 thr, 32 nodes/block. Gather: 16 groups x 16 lanes; group g owns 6 bins
// (b = bi*16+g -> node b&31, etype b>>5); lane owns DIN/16 contiguous cols.
// Counts + slot-vectors prefetched (independent loads); edges processed in
// 4-wide batches with clamp+zero-weight predication (independent row loads).
// GEMM: 4 waves; wave wv: rows (wv&1)*16, cols (wv>>1)*64; mfma_f32_16x16x32_bf16.
template <int DIN, bool BF16IN, bool BF16OUT>
__launch_bounds__(256)
__global__ void fused_layer_kernel(const void* __restrict__ feat_v,
                                   const int* __restrict__ slots,
                                   const int* __restrict__ cnt,
                                   const unsigned short* __restrict__ Wf,
                                   const float* __restrict__ bias,   // [3][128]
                                   void* __restrict__ out_v) {
    constexpr int K3 = 3 * DIN;
    constexpr int NK = K3 / 32;
    constexpr int SP = K3 + 8;          // padded LDS stride (bf16 units)
    __shared__ unsigned short s_a[32 * SP];   // 12.5 KB (L1) / 24.5 KB (L2)
    __shared__ float s_mask[NETY][32];

    const int t = threadIdx.x;
    const int n0 = blockIdx.x * 32;     // NN % 32 == 0
    const int g = t >> 4, sub = t & 15;

    // ---- phase A0: prefetch counts and slot-vectors for all 6 bins ----
    int cb[6], sl[6];
    #pragma unroll
    for (int bi = 0; bi < 6; ++bi) {
        const int b = bi * 16 + g;
        cb[bi] = cnt[(b >> 5) * NN + n0 + (b & 31)];
    }
    #pragma unroll
    for (int bi = 0; bi < 6; ++bi) {
        const int b = bi * 16 + g;
        sl[bi] = slots[((b >> 5) * NN + n0 + (b & 31)) * CAP + sub];
    }

    // ---- phase A1: per-bin means into s_a ----
    #pragma unroll
    for (int bi = 0; bi < 6; ++bi) {
        const int b = bi * 16 + g;
        const int nl = b & 31, e = b >> 5;
        const int c = cb[bi];
        const int sbase = ((e * NN) + n0 + nl) * CAP;
        const float inv = c > 0 ? 1.f / (float)c : 0.f;

        if constexpr (BF16IN) {
            const unsigned short* feat = (const unsigned short*)feat_v;
            float a[8] = {0.f, 0.f, 0.f, 0.f, 0.f, 0.f, 0.f, 0.f};
            for (int base = 0; base < c; base += 4) {
                const int cm1 = c - 1;
                const int j1 = base + 1 < c ? base + 1 : cm1;
                const int j2 = base + 2 < c ? base + 2 : cm1;
                const int j3 = base + 3 < c ? base + 3 : cm1;
                const float w1 = base + 1 < c ? 1.f : 0.f;
                const float w2 = base + 2 < c ? 1.f : 0.f;
                const float w3 = base + 3 < c ? 1.f : 0.f;
                const int s0 = get_slot(sl[bi], slots, sbase, base);
                const int s1 = get_slot(sl[bi], slots, sbase, j1);
                const int s2 = get_slot(sl[bi], slots, sbase, j2);
                const int s3 = get_slot(sl[bi], slots, sbase, j3);
                short8 u0 = *reinterpret_cast<const short8*>(feat + (size_t)s0 * DIN + sub * 8);
                short8 u1 = *reinterpret_cast<const short8*>(feat + (size_t)s1 * DIN + sub * 8);
                short8 u2 = *reinterpret_cast<const short8*>(feat + (size_t)s2 * DIN + sub * 8);
                short8 u3 = *reinterpret_cast<const short8*>(feat + (size_t)s3 * DIN + sub * 8);
                #pragma unroll
                for (int k = 0; k < 8; ++k) {
                    float acc = lrelu(bf2f((unsigned short)u0[k]));
                    acc = fmaf(w1, lrelu(bf2f((unsigned short)u1[k])), acc);
                    acc = fmaf(w2, lrelu(bf2f((unsigned short)u2[k])), acc);
                    acc = fmaf(w3, lrelu(bf2f((unsigned short)u3[k])), acc);
                    a[k] += acc;
                }
            }
            short8 o;
            #pragma unroll
            for (int k = 0; k < 8; ++k) o[k] = (short)f2bf(a[k] * inv);
            *reinterpret_cast<short8*>(&s_a[nl * SP + e * DIN + sub * 8]) = o;
        } else {
            const float* feat = (const float*)feat_v;
            float a[4] = {0.f, 0.f, 0.f, 0.f};
            for (int base = 0; base < c; base += 4) {
                const int cm1 = c - 1;
                const int j1 = base + 1 < c ? base + 1 : cm1;
                const int j2 = base + 2 < c ? base + 2 : cm1;
                const int j3 = base + 3 < c ? base + 3 : cm1;
                const float w1 = base + 1 < c ? 1.f : 0.f;
                const float w2 = base + 2 < c ? 1.f : 0.f;
                const float w3 = base + 3 < c ? 1.f : 0.f;
                const int s0 = get_slot(sl[bi], slots, sbase, base);
                const int s1 = get_slot(sl[bi], slots, sbase, j1);
                const int s2 = get_slot(sl[bi], slots, sbase, j2);
                const int s3 = get_slot(sl[bi], slots, sbase, j3);
                float4 v0 = *reinterpret_cast<const float4*>(feat + (size_t)s0 * DIN + sub * 4);
                float4 v1 = *reinterpret_cast<const float4*>(feat + (size_t)s1 * DIN + sub * 4);
                float4 v2 = *reinterpret_cast<const float4*>(feat + (size_t)s2 * DIN + sub * 4);
                float4 v3 = *reinterpret_cast<const float4*>(feat + (size_t)s3 * DIN + sub * 4);
                a[0] += v0.x + w1 * v1.x + w2 * v2.x + w3 * v3.x;
                a[1] += v0.y + w1 * v1.y + w2 * v2.y + w3 * v3.y;
                a[2] += v0.z + w1 * v1.z + w2 * v2.z + w3 * v3.z;
                a[3] += v0.w + w1 * v1.w + w2 * v2.w + w3 * v3.w;
            }
            short4v o;
            #pragma unroll
            for (int k = 0; k < 4; ++k) o[k] = (short)f2bf(a[k] * inv);
            *reinterpret_cast<short4v*>(&s_a[nl * SP + e * DIN + sub * 4]) = o;
        }
        if (sub == 0) s_mask[e][nl] = c > 0 ? 1.f : 0.f;
    }
    __syncthreads();

    // ---- phase B: [32 x K3] @ Wf -> [32 x 128] via MFMA ----
    const int wv = t >> 6, l = t & 63;
    const int rowbase = (wv & 1) * 16;
    const int nfbase = (wv >> 1) * 4;
    const int lr = l & 15, lk = l >> 4;

    f32x4 acc[4] = {{0.f,0.f,0.f,0.f},{0.f,0.f,0.f,0.f},{0.f,0.f,0.f,0.f},{0.f,0.f,0.f,0.f}};
    const unsigned short* sa = &s_a[(rowbase + lr) * SP + lk * 8];

    #pragma unroll
    for (int ks = 0; ks < NK; ++ks) {
        short8 af = *reinterpret_cast<const short8*>(sa + ks * 32);
        const unsigned short* wb = Wf + ((size_t)(ks * 8 + nfbase) * 64 + l) * 8;
        #pragma unroll
        for (int nf = 0; nf < 4; ++nf) {
            short8 bf = *reinterpret_cast<const short8*>(wb + (size_t)nf * 64 * 8);
            acc[nf] = __builtin_amdgcn_mfma_f32_16x16x32_bf16(af, bf, acc[nf], 0, 0, 0);
        }
    }

    // epilogue: D(row = rowbase + lk*4 + v, col = (nfbase+nf)*16 + lr) + masked bias
    #pragma unroll
    for (int nf = 0; nf < 4; ++nf) {
        const int col = (nfbase + nf) * 16 + lr;
        const float b0 = bias[0 * DH + col];
        const float b1 = bias[1 * DH + col];
        const float b2 = bias[2 * DH + col];
        #pragma unroll
        for (int v = 0; v < 4; ++v) {
            const int row = rowbase + lk * 4 + v;
            const float val = acc[nf][v] + s_mask[0][row] * b0
                                         + s_mask[1][row] * b1
                                         + s_mask[2][row] * b2;
            if constexpr (BF16OUT)
                ((unsigned short*)out_v)[(size_t)(n0 + row) * DH + col] = f2bf(val);
            else
                ((float*)out_v)[(size_t)(n0 + row) * DH + col] = val;
        }
    }
}

extern "C" void kernel_launch(void* const* d_in, const int* in_sizes, int n_in,
                              void* d_out, int out_size, void* d_ws, size_t ws_size,
                              hipStream_t stream) {
    const float* x   = (const float*)d_in[0];   // [NN, 64]
    const int* esrc  = (const int*)d_in[1];     // [3, EE]
    const int* edst  = (const int*)d_in[2];     // [3, EE]
    const float* W1  = (const float*)d_in[3];   // [3, 64, 128]
    const float* b1  = (const float*)d_in[4];   // [3, 128]
    const float* W2  = (const float*)d_in[5];   // [3, 128, 128]
    const float* b2  = (const float*)d_in[6];   // [3, 128]
    float* out = (float*)d_out;                 // [NN, 128] fp32

    // workspace layout (~65.4 MB)
    int* cnt    = (int*)d_ws;                               // [3*NN]
    int* slots  = cnt + NBINS;                              // [3*NN * CAP] = 38.4 MB
    unsigned short* Wf1 = (unsigned short*)(slots + (size_t)NBINS * CAP);  // [192*128]
    unsigned short* Wf2 = Wf1 + 192 * DH;                   // [384*128]
    unsigned short* h   = Wf2 + 384 * DH;                   // [NN*128] bf16

    // 1) zero bin counters
    hipMemsetAsync(cnt, 0, sizeof(int) * NBINS, stream);

    // 2) edge->slot scatter + W fragment prep (single kernel)
    scatter_wprep_kernel<<<SCAT_B + 12 + 24, 256, 0, stream>>>(
        esrc, edst, cnt, slots, W1, W2, Wf1, Wf2);

    // 3) layer 1: h = (concat_e mean_e(x)) @ W1 + masked bias   (bf16 out)
    fused_layer_kernel<64, false, true><<<NN / 32, 256, 0, stream>>>(
        x, slots, cnt, Wf1, b1, h);

    // 4) layer 2: out = (concat_e mean_e(lrelu(h))) @ W2 + masked bias   (fp32 out)
    fused_layer_kernel<128, true, false><<<NN / 32, 256, 0, stream>>>(
        h, slots, cnt, Wf2, b2, out);
}

// Round 9
// 200.525 us; speedup vs baseline: 5.2074x; 1.0346x over previous
//
#include <hip/hip_runtime.h>

#define NN 100000
#define NETY 3
#define EE 200000
#define DH 128
#define NBINS (NETY * NN)
#define CAP 32
#define SCAT_B ((NETY * EE + 255) / 256)   // 2344
#define XPREP_T (NN * 64 / 8)              // 800000 threads, 8 elems each
#define XPREP_B ((XPREP_T + 255) / 256)    // 3125

typedef __attribute__((ext_vector_type(8))) short short8;
typedef __attribute__((ext_vector_type(4))) short short4v;
typedef __attribute__((ext_vector_type(4))) float f32x4;

// ---------- bf16 helpers ----------
__device__ __forceinline__ float bf2f(unsigned short u) {
    return __uint_as_float(((unsigned int)u) << 16);
}
__device__ __forceinline__ unsigned short f2bf(float f) {
    unsigned int u = __float_as_uint(f);
    unsigned int r = ((u >> 16) & 1u) + 0x7fffu;   // round-to-nearest-even
    return (unsigned short)((u + r) >> 16);
}
__device__ __forceinline__ float lrelu(float f) {
    return f > 0.f ? f : 0.01f * f;
}

// ---------- W -> bf16 fragment-swizzled layout for mfma_f32_16x16x32_bf16 ----------
// Wf[((ks*8 + nf)*64 + l)*8 + j] = bf16( W[ks*32 + (l>>4)*8 + j][nf*16 + (l&15)] )
template <int K3>
__device__ __forceinline__ void wprep_body(const float* __restrict__ W,
                                           unsigned short* __restrict__ Wf, int tid) {
    int l = tid & 63;
    int nfks = tid >> 6;
    int nf = nfks & 7, ks = nfks >> 3;
    int k0 = ks * 32 + (l >> 4) * 8;
    int col = nf * 16 + (l & 15);
    short8 o;
    #pragma unroll
    for (int j = 0; j < 8; ++j)
        o[j] = (short)f2bf(W[(size_t)(k0 + j) * DH + col]);
    *reinterpret_cast<short8*>(Wf + (size_t)tid * 8) = o;
}

// ---------- one kernel: edge->slot scatter + both W preps + x->bf16 prep ----------
__global__ void scatter_wprep_kernel(const int* __restrict__ esrc,
                                     const int* __restrict__ edst,
                                     int* __restrict__ cnt, int* __restrict__ slots,
                                     const float* __restrict__ W1,
                                     const float* __restrict__ W2,
                                     unsigned short* __restrict__ Wf1,
                                     unsigned short* __restrict__ Wf2,
                                     const float* __restrict__ x,
                                     unsigned short* __restrict__ xb) {
    const int bid = blockIdx.x;
    if (bid < SCAT_B) {
        int tid = bid * 256 + threadIdx.x;
        if (tid < NETY * EE) {
            int e = tid / EE;
            int bin = e * NN + edst[tid];
            int pos = atomicAdd(&cnt[bin], 1);
            if (pos < CAP) slots[(size_t)bin * CAP + pos] = esrc[tid];
        }
    } else if (bid < SCAT_B + 12) {
        wprep_body<192>(W1, Wf1, (bid - SCAT_B) * 256 + threadIdx.x);
    } else if (bid < SCAT_B + 36) {
        wprep_body<384>(W2, Wf2, (bid - SCAT_B - 12) * 256 + threadIdx.x);
    } else {
        int tid = (bid - SCAT_B - 36) * 256 + threadIdx.x;
        if (tid < XPREP_T) {
            const float* p = x + (size_t)tid * 8;
            float4 v0 = *reinterpret_cast<const float4*>(p);
            float4 v1 = *reinterpret_cast<const float4*>(p + 4);
            short8 o;
            o[0] = (short)f2bf(v0.x); o[1] = (short)f2bf(v0.y);
            o[2] = (short)f2bf(v0.z); o[3] = (short)f2bf(v0.w);
            o[4] = (short)f2bf(v1.x); o[5] = (short)f2bf(v1.y);
            o[6] = (short)f2bf(v1.z); o[7] = (short)f2bf(v1.w);
            *reinterpret_cast<short8*>(xb + (size_t)tid * 8) = o;
        }
    }
}

// slot index j of a bin: register shfl for j<16, direct (rare, uniform) load for j>=16
__device__ __forceinline__ int get_slot(int slo, const int* __restrict__ slots,
                                        int sbase, int j) {
    int v = __shfl(slo, j & 15, 16);
    if (j >= 16) v = slots[sbase + j];
    return v;
}

// ---------- fused layer: 16 nodes/block; group g = node g x 3 etypes ----------
// Gather: prefetch counts+slots, issue all 12 row loads (3 etypes x batch-4) in one
// round (clamp+zero-weight predication; rare c>4 tail serial). Means -> bf16 LDS.
// GEMM: [16 x K3] @ Wf -> [16 x 128]; 4 waves x 2 nfrags; mfma_f32_16x16x32_bf16.
template <int DIN, bool LRELU_ON, bool BF16OUT>
__launch_bounds__(256)
__global__ void fused_layer_kernel(const unsigned short* __restrict__ feat,  // [NN][DIN] bf16
                                   const int* __restrict__ slots,
                                   const int* __restrict__ cnt,
                                   const unsigned short* __restrict__ Wf,
                                   const float* __restrict__ bias,   // [3][128]
                                   void* __restrict__ out_v) {
    constexpr int K3 = 3 * DIN;
    constexpr int NK = K3 / 32;
    constexpr int SP = K3 + 8;          // padded LDS stride (bf16 units)
    constexpr int CPL = DIN / 16;       // cols per lane: 4 (L1) / 8 (L2)
    __shared__ unsigned short s_a[16 * SP];   // 6.3 KB (L1) / 12.3 KB (L2)
    __shared__ float s_mask[NETY][16];

    const int t = threadIdx.x;
    const int n0 = blockIdx.x * 16;     // NN % 16 == 0
    const int g = t >> 4, sub = t & 15;
    const int node = n0 + g;

    // ---- prefetch counts and slot-vectors (independent loads) ----
    int cb[NETY], sl[NETY];
    #pragma unroll
    for (int e = 0; e < NETY; ++e) cb[e] = cnt[e * NN + node];
    #pragma unroll
    for (int e = 0; e < NETY; ++e)
        sl[e] = slots[(size_t)(e * NN + node) * CAP + sub];

    // ---- build first-batch indices/weights (register shfl, no memory) ----
    int sidx[NETY][4];
    float wgt[NETY][4];
    #pragma unroll
    for (int e = 0; e < NETY; ++e) {
        const int c = cb[e];
        const int cm1 = c > 0 ? c - 1 : 0;
        #pragma unroll
        for (int j = 0; j < 4; ++j) {
            const int jj = j < c ? j : cm1;      // jj < 16 always
            int sv = __shfl(sl[e], jj, 16);
            sidx[e][j] = c > 0 ? sv : 0;         // empty bin: slots hold poison -> row 0
            wgt[e][j] = j < c ? 1.f : 0.f;
        }
    }

    float a[NETY][CPL];
    #pragma unroll
    for (int e = 0; e < NETY; ++e)
        #pragma unroll
        for (int k = 0; k < CPL; ++k) a[e][k] = 0.f;

    // ---- issue all 12 row loads, then accumulate ----
    if constexpr (CPL == 8) {
        short8 u[NETY][4];
        #pragma unroll
        for (int e = 0; e < NETY; ++e)
            #pragma unroll
            for (int j = 0; j < 4; ++j)
                u[e][j] = *reinterpret_cast<const short8*>(
                    feat + (size_t)sidx[e][j] * DIN + sub * 8);
        #pragma unroll
        for (int e = 0; e < NETY; ++e)
            #pragma unroll
            for (int j = 0; j < 4; ++j)
                #pragma unroll
                for (int k = 0; k < 8; ++k) {
                    float f = bf2f((unsigned short)u[e][j][k]);
                    if constexpr (LRELU_ON) f = lrelu(f);
                    a[e][k] = fmaf(wgt[e][j], f, a[e][k]);
                }
    } else {
        short4v u[NETY][4];
        #pragma unroll
        for (int e = 0; e < NETY; ++e)
            #pragma unroll
            for (int j = 0; j < 4; ++j)
                u[e][j] = *reinterpret_cast<const short4v*>(
                    feat + (size_t)sidx[e][j] * DIN + sub * 4);
        #pragma unroll
        for (int e = 0; e < NETY; ++e)
            #pragma unroll
            for (int j = 0; j < 4; ++j)
                #pragma unroll
                for (int k = 0; k < 4; ++k) {
                    float f = bf2f((unsigned short)u[e][j][k]);
                    if constexpr (LRELU_ON) f = lrelu(f);
                    a[e][k] = fmaf(wgt[e][j], f, a[e][k]);
                }
    }

    // ---- rare tails (c > 4) ----
    #pragma unroll
    for (int e = 0; e < NETY; ++e) {
        const int c = cb[e];
        if (c > 4) {
            const int sbase = (e * NN + node) * CAP;
            for (int j = 4; j < c; ++j) {
                const int s = get_slot(sl[e], slots, sbase, j);
                if constexpr (CPL == 8) {
                    short8 u = *reinterpret_cast<const short8*>(
                        feat + (size_t)s * DIN + sub * 8);
                    #pragma unroll
                    for (int k = 0; k < 8; ++k) {
                        float f = bf2f((unsigned short)u[k]);
                        if constexpr (LRELU_ON) f = lrelu(f);
                        a[e][k] += f;
                    }
                } else {
                    short4v u = *reinterpret_cast<const short4v*>(
                        feat + (size_t)s * DIN + sub * 4);
                    #pragma unroll
                    for (int k = 0; k < 4; ++k) {
                        float f = bf2f((unsigned short)u[k]);
                        if constexpr (LRELU_ON) f = lrelu(f);
                        a[e][k] += f;
                    }
                }
            }
        }
    }

    // ---- means -> LDS, masks ----
    #pragma unroll
    for (int e = 0; e < NETY; ++e) {
        const int c = cb[e];
        const float inv = c > 0 ? 1.f / (float)c : 0.f;
        if constexpr (CPL == 8) {
            short8 o;
            #pragma unroll
            for (int k = 0; k < 8; ++k) o[k] = (short)f2bf(a[e][k] * inv);
            *reinterpret_cast<short8*>(&s_a[g * SP + e * DIN + sub * 8]) = o;
        } else {
            short4v o;
            #pragma unroll
            for (int k = 0; k < 4; ++k) o[k] = (short)f2bf(a[e][k] * inv);
            *reinterpret_cast<short4v*>(&s_a[g * SP + e * DIN + sub * 4]) = o;
        }
        if (sub == 0) s_mask[e][g] = c > 0 ? 1.f : 0.f;
    }
    __syncthreads();

    // ---- phase B: [16 x K3] @ Wf -> [16 x 128] ----
    const int wv = t >> 6, l = t & 63;
    const int lr = l & 15, lk = l >> 4;

    f32x4 acc[2] = {{0.f, 0.f, 0.f, 0.f}, {0.f, 0.f, 0.f, 0.f}};
    const unsigned short* sa = &s_a[lr * SP + lk * 8];

    #pragma unroll
    for (int ks = 0; ks < NK; ++ks) {
        short8 af = *reinterpret_cast<const short8*>(sa + ks * 32);
        const unsigned short* wb = Wf + ((size_t)(ks * 8 + wv * 2) * 64 + l) * 8;
        #pragma unroll
        for (int nf = 0; nf < 2; ++nf) {
            short8 bf = *reinterpret_cast<const short8*>(wb + (size_t)nf * 64 * 8);
            acc[nf] = __builtin_amdgcn_mfma_f32_16x16x32_bf16(af, bf, acc[nf], 0, 0, 0);
        }
    }

    // ---- epilogue: D(row = lk*4 + v, col = (wv*2+nf)*16 + lr) + masked bias ----
    #pragma unroll
    for (int nf = 0; nf < 2; ++nf) {
        const int col = (wv * 2 + nf) * 16 + lr;
        const float b0 = bias[0 * DH + col];
        const float b1 = bias[1 * DH + col];
        const float b2 = bias[2 * DH + col];
        #pragma unroll
        for (int v = 0; v < 4; ++v) {
            const int row = lk * 4 + v;
            const float val = acc[nf][v] + s_mask[0][row] * b0
                                         + s_mask[1][row] * b1
                                         + s_mask[2][row] * b2;
            if constexpr (BF16OUT)
                ((unsigned short*)out_v)[(size_t)(n0 + row) * DH + col] = f2bf(val);
            else
                ((float*)out_v)[(size_t)(n0 + row) * DH + col] = val;
        }
    }
}

extern "C" void kernel_launch(void* const* d_in, const int* in_sizes, int n_in,
                              void* d_out, int out_size, void* d_ws, size_t ws_size,
                              hipStream_t stream) {
    const float* x   = (const float*)d_in[0];   // [NN, 64]
    const int* esrc  = (const int*)d_in[1];     // [3, EE]
    const int* edst  = (const int*)d_in[2];     // [3, EE]
    const float* W1  = (const float*)d_in[3];   // [3, 64, 128]
    const float* b1  = (const float*)d_in[4];   // [3, 128]
    const float* W2  = (const float*)d_in[5];   // [3, 128, 128]
    const float* b2  = (const float*)d_in[6];   // [3, 128]
    float* out = (float*)d_out;                 // [NN, 128] fp32

    // workspace layout (~78 MB)
    int* cnt    = (int*)d_ws;                               // [3*NN]
    int* slots  = cnt + NBINS;                              // [3*NN * CAP] = 38.4 MB
    unsigned short* Wf1 = (unsigned short*)(slots + (size_t)NBINS * CAP);  // [192*128]
    unsigned short* Wf2 = Wf1 + 192 * DH;                   // [384*128]
    unsigned short* h   = Wf2 + 384 * DH;                   // [NN*128] bf16
    unsigned short* xb  = h + (size_t)NN * DH;              // [NN*64]  bf16

    // 1) zero bin counters
    hipMemsetAsync(cnt, 0, sizeof(int) * NBINS, stream);

    // 2) edge->slot scatter + W fragment prep + x->bf16 (single kernel)
    scatter_wprep_kernel<<<SCAT_B + 36 + XPREP_B, 256, 0, stream>>>(
        esrc, edst, cnt, slots, W1, W2, Wf1, Wf2, x, xb);

    // 3) layer 1: h = (concat_e mean_e(xb)) @ W1 + masked bias   (bf16 out)
    fused_layer_kernel<64, false, true><<<NN / 16, 256, 0, stream>>>(
        xb, slots, cnt, Wf1, b1, h);

    // 4) layer 2: out = (concat_e mean_e(lrelu(h))) @ W2 + masked bias   (fp32 out)
    fused_layer_kernel<128, true, false><<<NN / 16, 256, 0, stream>>>(
        h, slots, cnt, Wf2, b2, out);
}